// Round 4
// baseline (378.941 us; speedup 1.0000x reference)
//
#include <hip/hip_runtime.h>
#include <math.h>

#define NN 50000
#define FD 8
#define TD 12
#define HD 64
#define FT 96            // FD*TD floats per node
#define EE 1600000
#define NB 196           // ceil(NN/256) scan blocks
#define KC 8             // privatized counter copies

// Workspace layout in 4-byte units:
#define OFF_CNT    0                         // int[KC*NN] histogram copies (consumed by k_fill)
#define OFF_CTOT   (KC*NN)                   // int[NN] total counts
#define OFF_DINV   (KC*NN + NN)              // float[NN]
#define OFF_ROWST  (KC*NN + 2*NN)            // int[NN+1]
#define OFF_PART   (KC*NN + 3*NN + 16)       // int[256]
#define OFF_PARTEX (KC*NN + 3*NN + 16 + 256) // int[256]
#define OFF_ABSOFF (KC*NN + 3*NN + 1024)     // int[KC*NN] per-copy row bases
#define OFF_EDATA  (OFF_ABSOFF + KC*NN)      // int2[EE] (8B aligned)
#define OFF_AGG    (OFF_EDATA + 2*EE)        // float[NN*FT] (16B aligned)
#define OFF_FUSED  (OFF_AGG + NN*FT)         // float[1164]
// total ~= 8.95M units ~= 35.8 MB

__global__ void k_precompute(const float* __restrict__ conv_w,
                             const float* __restrict__ conv_b,
                             const float* __restrict__ lin_w,
                             const float* __restrict__ lin_b,
                             const float* __restrict__ attention,
                             float* __restrict__ fused) {
    int tid = threadIdx.x;
    // Wzz (0..511): f,h -> sum_k conv_w[f][k]    * lin_w[0][k][h]
    // Whh (512..1023):    sum_k conv_w[f][128+k] * lin_w[2][k][h]
    for (int idx = tid; idx < 1024; idx += blockDim.x) {
        int sel = idx >> 9;
        int f = (idx & 511) >> 6;
        int h = idx & 63;
        const float* cw = conv_w + f * 192 + (sel ? 128 : 0);
        const float* lw = lin_w + (sel ? 2 * 128 * 64 : 0) + h;
        float s = 0.f;
        for (int k = 0; k < 64; ++k) s += cw[k] * lw[k * 64];
        fused[idx] = s;
    }
    // bzz (1024..1087), bhh (1088..1151)
    for (int idx = tid; idx < 128; idx += blockDim.x) {
        int sel = idx >> 6;
        int h = idx & 63;
        const float* cb = conv_b + (sel ? 128 : 0);
        const float* lw = lin_w + (sel ? 2 * 128 * 64 : 0) + h;
        float s = lin_b[(sel ? 2 * 64 : 0) + h];
        for (int k = 0; k < 64; ++k) s += cb[k] * lw[k * 64];
        fused[1024 + idx] = s;
    }
    // probs (1152..1163): softmax(attention)
    if (tid == 0) {
        float m = attention[0];
        for (int t = 1; t < TD; ++t) m = fmaxf(m, attention[t]);
        float e[TD], sum = 0.f;
        for (int t = 0; t < TD; ++t) { e[t] = __expf(attention[t] - m); sum += e[t]; }
        for (int t = 0; t < TD; ++t) fused[1152 + t] = e[t] / sum;
    }
}

__global__ void k_zero(int* __restrict__ cnt) {
    int i = blockIdx.x * blockDim.x + threadIdx.x;
    if (i < KC * NN) cnt[i] = 0;
}

// dst histogram into KC privatized copies (copy chosen by edge-block -> low contention)
__global__ void k_count(const int* __restrict__ ei, int* __restrict__ cnt) {
    int e = blockIdx.x * blockDim.x + threadIdx.x;
    if (e >= EE) return;
    int k = (e >> 8) & (KC - 1);
    atomicAdd(&cnt[k * NN + ei[EE + e]], 1);
}

// total counts + block partial sums (for the scan)
__global__ void k_reduce(const int* __restrict__ cnt, int* __restrict__ ctot,
                         int* __restrict__ partial) {
    __shared__ int s[256];
    int i = blockIdx.x * 256 + threadIdx.x;
    int c = 0;
    if (i < NN) {
#pragma unroll
        for (int k = 0; k < KC; ++k) c += cnt[k * NN + i];
        ctot[i] = c;
    }
    s[threadIdx.x] = c;
    __syncthreads();
    for (int off = 128; off > 0; off >>= 1) {
        if (threadIdx.x < off) s[threadIdx.x] += s[threadIdx.x + off];
        __syncthreads();
    }
    if (threadIdx.x == 0) partial[blockIdx.x] = s[0];
}

__global__ void k_scan2(const int* __restrict__ partial, int* __restrict__ partialex) {
    __shared__ int s[256];
    int v = (threadIdx.x < NB) ? partial[threadIdx.x] : 0;
    s[threadIdx.x] = v;
    __syncthreads();
    for (int off = 1; off < 256; off <<= 1) {
        int t = (threadIdx.x >= off) ? s[threadIdx.x - off] : 0;
        __syncthreads();
        s[threadIdx.x] += t;
        __syncthreads();
    }
    partialex[threadIdx.x] = s[threadIdx.x] - v;   // exclusive
}

// rowstart + per-copy absolute sub-range bases
__global__ void k_scan3(const int* __restrict__ ctot, const int* __restrict__ cnt,
                        const int* __restrict__ partialex,
                        int* __restrict__ rowstart, int* __restrict__ absoff) {
    __shared__ int s[256];
    int i = blockIdx.x * 256 + threadIdx.x;
    int v = (i < NN) ? ctot[i] : 0;
    s[threadIdx.x] = v;
    __syncthreads();
    for (int off = 1; off < 256; off <<= 1) {
        int t = (threadIdx.x >= off) ? s[threadIdx.x - off] : 0;
        __syncthreads();
        s[threadIdx.x] += t;
        __syncthreads();
    }
    int excl = s[threadIdx.x] - v + partialex[blockIdx.x];
    if (i < NN) {
        rowstart[i] = excl;
        int base = excl;
#pragma unroll
        for (int k = 0; k < KC; ++k) {
            absoff[k * NN + i] = base;
            base += cnt[k * NN + i];
        }
        if (i == NN - 1) rowstart[NN] = excl + v;   // == EE
    }
}

// claim slot in this edge's copy sub-range; store (src, raw w)
__global__ void k_fill(const int* __restrict__ ei, const float* __restrict__ w,
                       const int* __restrict__ absoff, int* __restrict__ cnt,
                       int2* __restrict__ edata) {
    int e = blockIdx.x * blockDim.x + threadIdx.x;
    if (e >= EE) return;
    int s = ei[e], d = ei[EE + e];
    int k = (e >> 8) & (KC - 1);
    int pos = atomicSub(&cnt[k * NN + d], 1) - 1;
    edata[absoff[k * NN + d] + pos] = make_int2(s, __float_as_int(w[e]));
}

// exact weighted degree from CSR rows (no atomics) -> dinv
__global__ void k_deg(const int* __restrict__ rowstart, const int2* __restrict__ edata,
                      float* __restrict__ dinv) {
    int d = blockIdx.x * blockDim.x + threadIdx.x;
    if (d >= NN) return;
    int rs = rowstart[d], re = rowstart[d + 1];
    float s = 1.0f;   // self-loop
    for (int i = rs; i < re; ++i) s += __int_as_float(edata[i].y);
    dinv[d] = rsqrtf(s);
}

// patch edata.y in place: w -> dinv[src]*w
__global__ void k_coeff(const float* __restrict__ dinv, int2* __restrict__ edata) {
    int i = blockIdx.x * blockDim.x + threadIdx.x;
    if (i >= EE) return;
    int2 p = edata[i];
    p.y = __float_as_int(dinv[p.x] * __int_as_float(p.y));
    edata[i] = p;
}

// thread = (node, float4-chunk). 24 lanes share a node -> 384B coalesced x reads.
__global__ __launch_bounds__(256) void k_gather(const float* __restrict__ x,
                                                const float* __restrict__ dinv,
                                                const int* __restrict__ rowstart,
                                                const int2* __restrict__ edata,
                                                float* __restrict__ agg) {
    unsigned t = blockIdx.x * 256u + threadIdx.x;
    if (t >= (unsigned)NN * 24u) return;
    unsigned n = t / 24u;
    unsigned c = t - n * 24u;
    const float4* x4 = (const float4*)x;
    float dv = dinv[n];
    float4 a = x4[n * 24u + c];
    a.x *= dv; a.y *= dv; a.z *= dv; a.w *= dv;   // dinv[n]*x[n]
    int rs = rowstart[n], re = rowstart[n + 1];
    for (int k = rs; k < re; ++k) {
        int2 p = edata[k];
        float co = __int_as_float(p.y);           // dinv[s]*w
        float4 xv = x4[(unsigned)p.x * 24u + c];
        a.x += co * xv.x; a.y += co * xv.y; a.z += co * xv.z; a.w += co * xv.w;
    }
    a.x *= dv; a.y *= dv; a.z *= dv; a.w *= dv;   // outer dinv[n]
    ((float4*)agg)[n * 24u + c] = a;
}

// 4 threads per node, 16 h each; butterfly-reduce outT[12] over the 4 lanes
__global__ __launch_bounds__(256) void k_node(const float* __restrict__ agg,
                                              const float* __restrict__ fused,
                                              const float* __restrict__ cls_w,
                                              const float* __restrict__ cls_b,
                                              float* __restrict__ out) {
    __shared__ float sW[1164 + 768 + 12];
    for (int i = threadIdx.x; i < 1164 + 768; i += 256)
        sW[i] = (i < 1164) ? fused[i] : cls_w[i - 1164];
    if (threadIdx.x < 12) sW[1164 + 768 + threadIdx.x] = cls_b[threadIdx.x];
    __syncthreads();
    int n = blockIdx.x * 64 + (threadIdx.x >> 2);
    int q = threadIdx.x & 3;
    if (n >= NN) return;

    float r[FT];
    const float4* ap = (const float4*)(agg + (size_t)n * FT);
#pragma unroll
    for (int i = 0; i < FT / 4; ++i) {
        float4 v = ap[i];
        r[4 * i] = v.x; r[4 * i + 1] = v.y; r[4 * i + 2] = v.z; r[4 * i + 3] = v.w;
    }
    float outT[TD];
#pragma unroll
    for (int t = 0; t < TD; ++t) outT[t] = 0.f;

    const float* Wzz = sW;
    const float* Whh = sW + 512;
    const float* bzz = sW + 1024;
    const float* bhh = sW + 1088;
    const float* probs = sW + 1152;
    const float* cw = sW + 1164;

    for (int i = 0; i < 16; ++i) {
        int h = (q << 4) | i;
        float wz[FD], wh[FD];
#pragma unroll
        for (int f = 0; f < FD; ++f) { wz[f] = Wzz[f * 64 + h]; wh[f] = Whh[f * 64 + h]; }
        float acc = 0.f;
#pragma unroll
        for (int t = 0; t < TD; ++t) {
            float z = bzz[h], hh = bhh[h];
#pragma unroll
            for (int f = 0; f < FD; ++f) {
                float v = r[f * TD + t];
                z += v * wz[f];
                hh += v * wh[f];
            }
            float Z = 1.f / (1.f + __expf(-z));              // sigmoid
            float Ht = 1.f - 2.f / (1.f + __expf(2.f * hh)); // tanh
            acc += probs[t] * (1.f - Z) * Ht;
        }
        float rel = fmaxf(acc, 0.f);
#pragma unroll
        for (int t = 0; t < TD; ++t) outT[t] += rel * cw[h * TD + t];
    }
#pragma unroll
    for (int t = 0; t < TD; ++t) {
        outT[t] += __shfl_xor(outT[t], 1);
        outT[t] += __shfl_xor(outT[t], 2);
    }
    if (q == 0) {
        float* op = out + (size_t)n * TD;
#pragma unroll
        for (int t = 0; t < TD; ++t) op[t] = outT[t] + sW[1164 + 768 + t];
    }
}

extern "C" void kernel_launch(void* const* d_in, const int* in_sizes, int n_in,
                              void* d_out, int out_size, void* d_ws, size_t ws_size,
                              hipStream_t stream) {
    const float* x         = (const float*)d_in[0];
    const int*   ei        = (const int*)d_in[1];
    const float* w         = (const float*)d_in[2];
    const float* conv_w    = (const float*)d_in[3];
    const float* conv_b    = (const float*)d_in[4];
    const float* lin_w     = (const float*)d_in[5];
    const float* lin_b     = (const float*)d_in[6];
    const float* attention = (const float*)d_in[7];
    const float* cls_w     = (const float*)d_in[8];
    const float* cls_b     = (const float*)d_in[9];
    float* ws  = (float*)d_ws;
    float* out = (float*)d_out;

    int*   cnt       = (int*)(ws + OFF_CNT);
    int*   ctot      = (int*)(ws + OFF_CTOT);
    float* dinv      = ws + OFF_DINV;
    int*   rowstart  = (int*)(ws + OFF_ROWST);
    int*   partial   = (int*)(ws + OFF_PART);
    int*   partialex = (int*)(ws + OFF_PARTEX);
    int*   absoff    = (int*)(ws + OFF_ABSOFF);
    int2*  edata     = (int2*)(ws + OFF_EDATA);
    float* agg       = ws + OFF_AGG;
    float* fused     = ws + OFF_FUSED;

    k_precompute<<<1, 256, 0, stream>>>(conv_w, conv_b, lin_w, lin_b, attention, fused);
    k_zero<<<(KC * NN + 255) / 256, 256, 0, stream>>>(cnt);
    k_count<<<(EE + 255) / 256, 256, 0, stream>>>(ei, cnt);
    k_reduce<<<NB, 256, 0, stream>>>(cnt, ctot, partial);
    k_scan2<<<1, 256, 0, stream>>>(partial, partialex);
    k_scan3<<<NB, 256, 0, stream>>>(ctot, cnt, partialex, rowstart, absoff);
    k_fill<<<(EE + 255) / 256, 256, 0, stream>>>(ei, w, absoff, cnt, edata);
    k_deg<<<(NN + 255) / 256, 256, 0, stream>>>(rowstart, edata, dinv);
    k_coeff<<<(EE + 255) / 256, 256, 0, stream>>>(dinv, edata);
    {
        unsigned total = (unsigned)NN * 24u;   // 1.2M threads
        k_gather<<<(total + 255) / 256, 256, 0, stream>>>(x, dinv, rowstart, edata, agg);
    }
    k_node<<<(NN + 63) / 64, 256, 0, stream>>>(agg, fused, cls_w, cls_b, out);
}